// Round 7
// baseline (136.043 us; speedup 1.0000x reference)
//
#include <hip/hip_runtime.h>
#include <math.h>

// SquaredGaussianMixture: N=2M points, D=4, K=8, scalar f32 output.
//
// Round-6 (resubmit after broker timeout): __launch_bounds__(256,1).
// Root cause of R1-R5 slowness: without launch_bounds the compiler caps
// VGPRs at 64 (assumes 1024-thread blocks); the ~150 per-thread coefficients
// then spill/rematerialize through L1/L2 every point (VALUBusy 14%, HBM 3%).
// With a 256-VGPR budget everything lives in registers and the loop is pure
// FMA + exp2.
// Per point: d_k = exp2(-||G''_k x + t_k||^2)  (14 fma + 1 exp2 each)
//            s   = sum_{i<=j} W2'_ij d_i d_j   (44 fma; W2' has 2^{cc_i+cc_j}
//                                               and the off-diag 2x folded in)

struct WsLayout {
  double tot[512];   // 64 slots at 64B stride for atomic spreading
  double logz;
  unsigned int ctr;
  unsigned int pad_;
  float par[148];    // [k*14+0..9]=G'' tri, [+10..13]=t; [112+u]=W2' (36)
};

__device__ inline void chol4(const double S[4][4], double G[4][4]) {
  #pragma unroll
  for (int i = 0; i < 4; ++i) {
    #pragma unroll
    for (int j = 0; j < 4; ++j) {
      if (j > i) { G[i][j] = 0.0; continue; }
      double s = S[i][j];
      #pragma unroll
      for (int m = 0; m < 4; ++m) if (m < j) s -= G[i][m] * G[j][m];
      if (i == j) G[i][j] = sqrt(s);
      else        G[i][j] = s / G[j][j];
    }
  }
}

__global__ void prep_kernel(const float* __restrict__ means,
                            const float* __restrict__ chols,
                            const float* __restrict__ weights,
                            WsLayout* ws) {
  __shared__ double sig[8][4][4];
  __shared__ double ccs[8];  // log2 of per-cluster coefficient
  const double LOG2E = 1.4426950408889634074;
  const double LN2PI = 1.8378770664093454836;
  const int t = threadIdx.x;  // 0..63, one wave

  if (t < 8) {
    const int k = t;
    double L[4][4], S[4][4];
    #pragma unroll
    for (int i = 0; i < 4; ++i)
      #pragma unroll
      for (int j = 0; j < 4; ++j)
        L[i][j] = (j <= i) ? (double)chols[k * 16 + i * 4 + j] : 0.0;
    #pragma unroll
    for (int i = 0; i < 4; ++i)
      #pragma unroll
      for (int j = 0; j < 4; ++j) {
        double s = (i == j) ? 1.0 : 0.0;
        #pragma unroll
        for (int m = 0; m < 4; ++m) s += L[i][m] * L[j][m];
        S[i][j] = s;
        sig[k][i][j] = s;
      }
    double G[4][4];
    chol4(S, G);
    const double logdet =
        2.0 * (log(G[0][0]) + log(G[1][1]) + log(G[2][2]) + log(G[3][3]));
    // invert lower-triangular G
    double Gi[4][4];
    #pragma unroll
    for (int j = 0; j < 4; ++j) {
      #pragma unroll
      for (int i = 0; i < 4; ++i) {
        if (i < j) { Gi[i][j] = 0.0; continue; }
        double s = (i == j) ? 1.0 : 0.0;
        #pragma unroll
        for (int m = 0; m < 4; ++m)
          if (m >= j && m < i) s -= G[i][m] * Gi[m][j];
        Gi[i][j] = s / G[i][i];
      }
    }
    // d = exp2(-||G''x + t||^2), G'' = sqrt(0.5*log2e) * Gi, t = -G''*mu
    const double sc = sqrt(0.5 * LOG2E);
    double mu[4];
    #pragma unroll
    for (int i = 0; i < 4; ++i) mu[i] = (double)means[k * 4 + i];
    int idx = 0;
    #pragma unroll
    for (int i = 0; i < 4; ++i) {
      double ti = 0.0;
      #pragma unroll
      for (int j = 0; j < 4; ++j) {
        const double gij = sc * Gi[i][j];
        if (j <= i) ws->par[k * 14 + (idx++)] = (float)gij;
        ti += gij * mu[j];
      }
      ws->par[k * 14 + 10 + i] = (float)(-ti);
    }
    ccs[k] = LOG2E * (-0.5 * (4.0 * LN2PI + logdet));  // log2(coef_k)
  }
  __syncthreads();

  // pairwise part: one thread per (i,j) of 8x8
  const int i = t >> 3, j = t & 7;
  const double wij = (double)weights[i] * (double)weights[j];
  double m = wij;
  #pragma unroll
  for (int o = 32; o > 0; o >>= 1) {
    double x = __shfl_xor(m, o, 64);
    m = fmax(m, x);
  }
  const double e = exp(wij - m);
  double ssum = e;
  #pragma unroll
  for (int o = 32; o > 0; o >>= 1) ssum += __shfl_xor(ssum, o, 64);
  const double Wij = e / ssum;

  // packed upper-tri weight: softmax * coef_i * coef_j, off-diag doubled
  if (i <= j) {
    const int u = 8 * i - (i * (i - 1)) / 2 + (j - i);
    const double scale = exp2(ccs[i] + ccs[j]) * ((i == j) ? 1.0 : 2.0);
    ws->par[112 + u] = (float)(Wij * scale);
  }

  double SS[4][4];
  #pragma unroll
  for (int a = 0; a < 4; ++a)
    #pragma unroll
    for (int b = 0; b < 4; ++b) SS[a][b] = sig[i][a][b] + sig[j][a][b];
  double G2[4][4];
  chol4(SS, G2);
  const double logdetS =
      2.0 * (log(G2[0][0]) + log(G2[1][1]) + log(G2[2][2]) + log(G2[3][3]));
  double bvec[4], y[4];
  #pragma unroll
  for (int a = 0; a < 4; ++a)
    bvec[a] = (double)means[i * 4 + a] - (double)means[j * 4 + a];
  #pragma unroll
  for (int a = 0; a < 4; ++a) {
    double s = bvec[a];
    #pragma unroll
    for (int mm = 0; mm < 4; ++mm) if (mm < a) s -= G2[a][mm] * y[mm];
    y[a] = s / G2[a][a];
  }
  const double md = y[0]*y[0] + y[1]*y[1] + y[2]*y[2] + y[3]*y[3];
  double zterm = Wij * exp(-0.5 * md - 0.5 * (4.0 * LN2PI + logdetS));
  #pragma unroll
  for (int o = 32; o > 0; o >>= 1) zterm += __shfl_xor(zterm, o, 64);
  if (t == 0) { ws->logz = log(zterm); ws->ctr = 0u; }

  // zero the atomic slots (ws is poisoned 0xAA before every call)
  for (int u = t; u < 512; u += 64) ws->tot[u] = 0.0;
}

// per-point density-pair sum; 157 fma + 8 exp2, no cross-lane ops
__device__ inline float point_s(const float4 v, const float g[8][10],
                                const float tn[8][4], const float W2[36]) {
  float d[8];
  #pragma unroll
  for (int k = 0; k < 8; ++k) {
    const float y0 = fmaf(g[k][0], v.x, tn[k][0]);
    const float y1 = fmaf(g[k][2], v.y, fmaf(g[k][1], v.x, tn[k][1]));
    const float y2 =
        fmaf(g[k][5], v.z, fmaf(g[k][4], v.y, fmaf(g[k][3], v.x, tn[k][2])));
    const float y3 = fmaf(
        g[k][9], v.w,
        fmaf(g[k][8], v.z, fmaf(g[k][7], v.y, fmaf(g[k][6], v.x, tn[k][3]))));
    float q = y0 * y0;
    q = fmaf(y1, y1, q);
    q = fmaf(y2, y2, q);
    q = fmaf(y3, y3, q);
    d[k] = __builtin_amdgcn_exp2f(-q);  // negation via input modifier
  }
  float s = 0.0f;
  int u = 0;
  #pragma unroll
  for (int i = 0; i < 8; ++i) {
    float tt = W2[u++] * d[i];  // j == i term
    #pragma unroll
    for (int j = i + 1; j < 8; ++j) tt = fmaf(W2[u++], d[j], tt);
    s = fmaf(d[i], tt, s);
  }
  return s;
}

__global__ __launch_bounds__(256, 1) void point_kernel(
    const float4* __restrict__ X, const WsLayout* __restrict__ wsc,
    double* __restrict__ tot, unsigned int* ctr, float* __restrict__ out,
    int n) {
  const int lane = threadIdx.x & 63;
  const int wid = threadIdx.x >> 6;
  const float* par = wsc->par;

  float g[8][10], tn[8][4], W2[36];
  #pragma unroll
  for (int k = 0; k < 8; ++k) {
    #pragma unroll
    for (int u = 0; u < 10; ++u) g[k][u] = par[k * 14 + u];
    #pragma unroll
    for (int u = 0; u < 4; ++u) tn[k][u] = par[k * 14 + 10 + u];
  }
  #pragma unroll
  for (int u = 0; u < 36; ++u) W2[u] = par[112 + u];

  // Opaque defs: allocator cannot rematerialize the loads, so with the
  // 256-VGPR budget these 148 values stay register-resident across the loop.
  #pragma unroll
  for (int k = 0; k < 8; ++k) {
    #pragma unroll
    for (int u = 0; u < 10; ++u) asm("" : "+v"(g[k][u]));
    #pragma unroll
    for (int u = 0; u < 4; ++u) asm("" : "+v"(tn[k][u]));
  }
  #pragma unroll
  for (int u = 0; u < 36; ++u) asm("" : "+v"(W2[u]));

  const int S = gridDim.x * blockDim.x;  // 262144
  float sacc = 0.0f;
  int i = blockIdx.x * blockDim.x + threadIdx.x;
  for (; i + 3 * S < n; i += 4 * S) {  // 4 independent loads in flight
    const float4 v0 = X[i];
    const float4 v1 = X[i + S];
    const float4 v2 = X[i + 2 * S];
    const float4 v3 = X[i + 3 * S];
    sacc += point_s(v0, g, tn, W2);
    sacc += point_s(v1, g, tn, W2);
    sacc += point_s(v2, g, tn, W2);
    sacc += point_s(v3, g, tn, W2);
  }
  for (; i < n; i += S) sacc += point_s(X[i], g, tn, W2);

  // block reduce: f64 wave butterfly -> LDS -> one atomic per block
  double bs = (double)sacc;
  #pragma unroll
  for (int o = 32; o > 0; o >>= 1) bs += __shfl_xor(bs, o, 64);
  __shared__ double lred[4];
  if (lane == 0) lred[wid] = bs;
  __syncthreads();
  if (threadIdx.x == 0) {
    const double v = lred[0] + lred[1] + lred[2] + lred[3];
    unsafeAtomicAdd(&tot[(blockIdx.x & 63) * 8], v);  // 64 slots, 64B apart
  }
  __syncthreads();

  __shared__ int amLast;
  if (threadIdx.x == 0) {
    __threadfence();
    const unsigned int old = atomicAdd(ctr, 1u);
    amLast = (old == gridDim.x - 1u);
    __threadfence();
  }
  __syncthreads();
  if (amLast && threadIdx.x < 64) {
    // atomic reads — same coherence path as the slot writes
    double val = unsafeAtomicAdd(&tot[threadIdx.x * 8], 0.0);
    #pragma unroll
    for (int o = 32; o > 0; o >>= 1) val += __shfl_xor(val, o, 64);
    if (threadIdx.x == 0)
      out[0] = (float)(-(log(val) - wsc->logz) / (double)n);
  }
}

extern "C" void kernel_launch(void* const* d_in, const int* in_sizes, int n_in,
                              void* d_out, int out_size, void* d_ws, size_t ws_size,
                              hipStream_t stream) {
  const float* X       = (const float*)d_in[0];
  const float* means   = (const float*)d_in[1];
  const float* chols   = (const float*)d_in[2];
  const float* weights = (const float*)d_in[3];
  const int npoints = in_sizes[0] / 4;  // 2,000,000

  WsLayout* ws = (WsLayout*)d_ws;
  prep_kernel<<<1, 64, 0, stream>>>(means, chols, weights, ws);
  point_kernel<<<1024, 256, 0, stream>>>((const float4*)X, ws, ws->tot,
                                         &ws->ctr, (float*)d_out, npoints);
}

// Round 8
// 119.656 us; speedup vs baseline: 1.1369x; 1.1369x over previous
//
#include <hip/hip_runtime.h>
#include <math.h>

// SquaredGaussianMixture: N=2M points, D=4, K=8, scalar f32 output.
//
// Round-8: REMOVED the asm("+v") pins. Post-mortem of R5/R7: the pins forced
// all 148 wave-uniform coefficients into per-lane VGPRs (instead of SGPRs,
// where uniform s_loads naturally live and cost zero VGPRs), inflating VGPR
// demand past every cap and CAUSING the spills they were meant to prevent.
// Also: uniform trip count (nb=2) with masked loads + software prefetch of
// the next 4-point batch, so HBM latency hides under ~1300 cyc of FMA work.
// Per point: d_k = exp2(-||G''_k x + t_k||^2)  (14 fma + 1 exp2 each)
//            s   = sum_{i<=j} W2'_ij d_i d_j   (44 fma; W2' has 2^{cc_i+cc_j}
//                                               and the off-diag 2x folded in)

struct WsLayout {
  double tot[512];   // 64 slots at 64B stride for atomic spreading
  double logz;
  unsigned int ctr;
  unsigned int pad_;
  float par[148];    // [k*14+0..9]=G'' tri, [+10..13]=t; [112+u]=W2' (36)
};

__device__ inline void chol4(const double S[4][4], double G[4][4]) {
  #pragma unroll
  for (int i = 0; i < 4; ++i) {
    #pragma unroll
    for (int j = 0; j < 4; ++j) {
      if (j > i) { G[i][j] = 0.0; continue; }
      double s = S[i][j];
      #pragma unroll
      for (int m = 0; m < 4; ++m) if (m < j) s -= G[i][m] * G[j][m];
      if (i == j) G[i][j] = sqrt(s);
      else        G[i][j] = s / G[j][j];
    }
  }
}

__global__ void prep_kernel(const float* __restrict__ means,
                            const float* __restrict__ chols,
                            const float* __restrict__ weights,
                            WsLayout* ws) {
  __shared__ double sig[8][4][4];
  __shared__ double ccs[8];  // log2 of per-cluster coefficient
  const double LOG2E = 1.4426950408889634074;
  const double LN2PI = 1.8378770664093454836;
  const int t = threadIdx.x;  // 0..63, one wave

  if (t < 8) {
    const int k = t;
    double L[4][4], S[4][4];
    #pragma unroll
    for (int i = 0; i < 4; ++i)
      #pragma unroll
      for (int j = 0; j < 4; ++j)
        L[i][j] = (j <= i) ? (double)chols[k * 16 + i * 4 + j] : 0.0;
    #pragma unroll
    for (int i = 0; i < 4; ++i)
      #pragma unroll
      for (int j = 0; j < 4; ++j) {
        double s = (i == j) ? 1.0 : 0.0;
        #pragma unroll
        for (int m = 0; m < 4; ++m) s += L[i][m] * L[j][m];
        S[i][j] = s;
        sig[k][i][j] = s;
      }
    double G[4][4];
    chol4(S, G);
    const double logdet =
        2.0 * (log(G[0][0]) + log(G[1][1]) + log(G[2][2]) + log(G[3][3]));
    // invert lower-triangular G
    double Gi[4][4];
    #pragma unroll
    for (int j = 0; j < 4; ++j) {
      #pragma unroll
      for (int i = 0; i < 4; ++i) {
        if (i < j) { Gi[i][j] = 0.0; continue; }
        double s = (i == j) ? 1.0 : 0.0;
        #pragma unroll
        for (int m = 0; m < 4; ++m)
          if (m >= j && m < i) s -= G[i][m] * Gi[m][j];
        Gi[i][j] = s / G[i][i];
      }
    }
    // d = exp2(-||G''x + t||^2), G'' = sqrt(0.5*log2e) * Gi, t = -G''*mu
    const double sc = sqrt(0.5 * LOG2E);
    double mu[4];
    #pragma unroll
    for (int i = 0; i < 4; ++i) mu[i] = (double)means[k * 4 + i];
    int idx = 0;
    #pragma unroll
    for (int i = 0; i < 4; ++i) {
      double ti = 0.0;
      #pragma unroll
      for (int j = 0; j < 4; ++j) {
        const double gij = sc * Gi[i][j];
        if (j <= i) ws->par[k * 14 + (idx++)] = (float)gij;
        ti += gij * mu[j];
      }
      ws->par[k * 14 + 10 + i] = (float)(-ti);
    }
    ccs[k] = LOG2E * (-0.5 * (4.0 * LN2PI + logdet));  // log2(coef_k)
  }
  __syncthreads();

  // pairwise part: one thread per (i,j) of 8x8
  const int i = t >> 3, j = t & 7;
  const double wij = (double)weights[i] * (double)weights[j];
  double m = wij;
  #pragma unroll
  for (int o = 32; o > 0; o >>= 1) {
    double x = __shfl_xor(m, o, 64);
    m = fmax(m, x);
  }
  const double e = exp(wij - m);
  double ssum = e;
  #pragma unroll
  for (int o = 32; o > 0; o >>= 1) ssum += __shfl_xor(ssum, o, 64);
  const double Wij = e / ssum;

  // packed upper-tri weight: softmax * coef_i * coef_j, off-diag doubled
  if (i <= j) {
    const int u = 8 * i - (i * (i - 1)) / 2 + (j - i);
    const double scale = exp2(ccs[i] + ccs[j]) * ((i == j) ? 1.0 : 2.0);
    ws->par[112 + u] = (float)(Wij * scale);
  }

  double SS[4][4];
  #pragma unroll
  for (int a = 0; a < 4; ++a)
    #pragma unroll
    for (int b = 0; b < 4; ++b) SS[a][b] = sig[i][a][b] + sig[j][a][b];
  double G2[4][4];
  chol4(SS, G2);
  const double logdetS =
      2.0 * (log(G2[0][0]) + log(G2[1][1]) + log(G2[2][2]) + log(G2[3][3]));
  double bvec[4], y[4];
  #pragma unroll
  for (int a = 0; a < 4; ++a)
    bvec[a] = (double)means[i * 4 + a] - (double)means[j * 4 + a];
  #pragma unroll
  for (int a = 0; a < 4; ++a) {
    double s = bvec[a];
    #pragma unroll
    for (int mm = 0; mm < 4; ++mm) if (mm < a) s -= G2[a][mm] * y[mm];
    y[a] = s / G2[a][a];
  }
  const double md = y[0]*y[0] + y[1]*y[1] + y[2]*y[2] + y[3]*y[3];
  double zterm = Wij * exp(-0.5 * md - 0.5 * (4.0 * LN2PI + logdetS));
  #pragma unroll
  for (int o = 32; o > 0; o >>= 1) zterm += __shfl_xor(zterm, o, 64);
  if (t == 0) { ws->logz = log(zterm); ws->ctr = 0u; }

  // zero the atomic slots (ws is poisoned 0xAA before every call)
  for (int u = t; u < 512; u += 64) ws->tot[u] = 0.0;
}

// per-point density-pair sum; 157 fma + 8 exp2, no cross-lane ops
__device__ inline float point_s(const float4 v, const float g[8][10],
                                const float tn[8][4], const float W2[36]) {
  float d[8];
  #pragma unroll
  for (int k = 0; k < 8; ++k) {
    const float y0 = fmaf(g[k][0], v.x, tn[k][0]);
    const float y1 = fmaf(g[k][2], v.y, fmaf(g[k][1], v.x, tn[k][1]));
    const float y2 =
        fmaf(g[k][5], v.z, fmaf(g[k][4], v.y, fmaf(g[k][3], v.x, tn[k][2])));
    const float y3 = fmaf(
        g[k][9], v.w,
        fmaf(g[k][8], v.z, fmaf(g[k][7], v.y, fmaf(g[k][6], v.x, tn[k][3]))));
    float q = y0 * y0;
    q = fmaf(y1, y1, q);
    q = fmaf(y2, y2, q);
    q = fmaf(y3, y3, q);
    d[k] = __builtin_amdgcn_exp2f(-q);  // negation via input modifier
  }
  float s = 0.0f;
  int u = 0;
  #pragma unroll
  for (int i = 0; i < 8; ++i) {
    float tt = W2[u++] * d[i];  // j == i term
    #pragma unroll
    for (int j = i + 1; j < 8; ++j) tt = fmaf(W2[u++], d[j], tt);
    s = fmaf(d[i], tt, s);
  }
  return s;
}

__global__ __launch_bounds__(256, 2) void point_kernel(
    const float4* __restrict__ X, const WsLayout* __restrict__ wsc,
    double* __restrict__ tot, unsigned int* ctr, float* __restrict__ out,
    int n) {
  const int lane = threadIdx.x & 63;
  const int wid = threadIdx.x >> 6;
  const float* par = wsc->par;

  // Wave-uniform coefficient loads. NO asm pins: the compiler keeps these in
  // SGPRs (s_load) where they cost zero VGPRs; ~40 overflow values become
  // VGPR copies, still well under the 256-VGPR budget of (256,2).
  float g[8][10], tn[8][4], W2[36];
  #pragma unroll
  for (int k = 0; k < 8; ++k) {
    #pragma unroll
    for (int u = 0; u < 10; ++u) g[k][u] = par[k * 14 + u];
    #pragma unroll
    for (int u = 0; u < 4; ++u) tn[k][u] = par[k * 14 + 10 + u];
  }
  #pragma unroll
  for (int u = 0; u < 36; ++u) W2[u] = par[112 + u];

  const int S = gridDim.x * blockDim.x;      // 262144
  const int idx = blockIdx.x * blockDim.x + threadIdx.x;
  const int nb = (n + 4 * S - 1) / (4 * S);  // uniform trip count (=2)

  // masked load of batch 0; poison v.x so q = inf -> d = 0 for invalid pts
  float4 v[4];
  #pragma unroll
  for (int j = 0; j < 4; ++j) {
    const int ij = idx + j * S;
    const bool ok = ij < n;
    v[j] = X[ok ? ij : 0];
    v[j].x = ok ? v[j].x : 1e18f;
  }

  float sacc = 0.0f;
  for (int b = 0; b < nb; ++b) {
    float4 vn[4];
    const bool more = (b + 1 < nb);
    if (more) {  // prefetch next batch before computing current one
      const int base = idx + (b + 1) * 4 * S;
      #pragma unroll
      for (int j = 0; j < 4; ++j) {
        const int ij = base + j * S;
        const bool ok = ij < n;
        vn[j] = X[ok ? ij : 0];
        vn[j].x = ok ? vn[j].x : 1e18f;
      }
    }
    #pragma unroll
    for (int j = 0; j < 4; ++j) sacc += point_s(v[j], g, tn, W2);
    if (more) {
      #pragma unroll
      for (int j = 0; j < 4; ++j) v[j] = vn[j];
    }
  }

  // block reduce: f64 wave butterfly -> LDS -> one atomic per block
  double bs = (double)sacc;
  #pragma unroll
  for (int o = 32; o > 0; o >>= 1) bs += __shfl_xor(bs, o, 64);
  __shared__ double lred[4];
  if (lane == 0) lred[wid] = bs;
  __syncthreads();
  if (threadIdx.x == 0) {
    const double vsum = lred[0] + lred[1] + lred[2] + lred[3];
    unsafeAtomicAdd(&tot[(blockIdx.x & 63) * 8], vsum);  // 64 slots, 64B apart
  }
  __syncthreads();

  __shared__ int amLast;
  if (threadIdx.x == 0) {
    __threadfence();
    const unsigned int old = atomicAdd(ctr, 1u);
    amLast = (old == gridDim.x - 1u);
    __threadfence();
  }
  __syncthreads();
  if (amLast && threadIdx.x < 64) {
    // atomic reads — same coherence path as the slot writes
    double val = unsafeAtomicAdd(&tot[threadIdx.x * 8], 0.0);
    #pragma unroll
    for (int o = 32; o > 0; o >>= 1) val += __shfl_xor(val, o, 64);
    if (threadIdx.x == 0)
      out[0] = (float)(-(log(val) - wsc->logz) / (double)n);
  }
}

extern "C" void kernel_launch(void* const* d_in, const int* in_sizes, int n_in,
                              void* d_out, int out_size, void* d_ws, size_t ws_size,
                              hipStream_t stream) {
  const float* X       = (const float*)d_in[0];
  const float* means   = (const float*)d_in[1];
  const float* chols   = (const float*)d_in[2];
  const float* weights = (const float*)d_in[3];
  const int npoints = in_sizes[0] / 4;  // 2,000,000

  WsLayout* ws = (WsLayout*)d_ws;
  prep_kernel<<<1, 64, 0, stream>>>(means, chols, weights, ws);
  point_kernel<<<1024, 256, 0, stream>>>((const float4*)X, ws, ws->tot,
                                         &ws->ctr, (float*)d_out, npoints);
}